// Round 1
// baseline (745.975 us; speedup 1.0000x reference)
//
#include <hip/hip_runtime.h>
#include <hip/hip_bf16.h>

// Problem constants (VectorQuantizer): B=16, D=256, T=2048, K=1024, N=B*T=32768
// inputs: [B, D, T] fp32 ; embeddings: [K, D] fp32
// outputs (concat, fp32): quantized_st [B,D,T] (8388608) | loss | e_latent | q_latent | indices [32768]
#define NB 16
#define ND 256
#define NT 2048
#define NK 1024
#define NN (NB * NT)          // 32768
#define QSIZE (NB * ND * NT)  // 8388608
#define SCL_OFF QSIZE         // 3 scalars
#define IDX_OFF (QSIZE + 3)

// ---------------- Kernel 0: e2[k] = sum_d e[k][d]^2 (fp64); also zero the mse accumulator
__global__ __launch_bounds__(64) void vq_e2(const float4* __restrict__ E4,
                                            double* __restrict__ e2,
                                            double* __restrict__ accum) {
    int k = blockIdx.x;
    int lane = threadIdx.x;
    float4 v = E4[k * 64 + lane];
    double s = (double)v.x * v.x + (double)v.y * v.y + (double)v.z * v.z + (double)v.w * v.w;
    #pragma unroll
    for (int off = 32; off; off >>= 1) s += __shfl_down(s, off, 64);
    if (lane == 0) e2[k] = s;
    if (k == 0 && lane == 0) accum[0] = 0.0;
}

// ---------------- Kernel A: per-row argmin over K of s = e2[k] - 2*(x . e[k]), fp64 accumulate
// Block: 256 threads, 32 rows (consecutive n => same b, consecutive t).
// Thread (rg = tid&7, kg = tid>>3): rows {rg, rg+8, rg+16, rg+24}, k in {kp*128 + kg*4 + kk}.
__global__ __launch_bounds__(256) void vq_argmin(const float* __restrict__ X,
                                                 const float4* __restrict__ E4,
                                                 const double* __restrict__ e2,
                                                 int* __restrict__ idx_ws,
                                                 float* __restrict__ out) {
    __shared__ float Xl[32 * 260];       // stride 260: conflict-free b128 reads for row-stride-8 lanes
    __shared__ double sm_m[32][32];
    __shared__ int    sm_i[32][32];

    const int tid = threadIdx.x;
    const int n0  = blockIdx.x * 32;
    const int b   = n0 >> 11;            // n0 / NT
    const int t0  = n0 & (NT - 1);
    const float* Xb = X + (size_t)b * (ND * NT) + t0;

    // Stage X tile: element (r, d) = inputs[b][d][t0 + r]; lanes contiguous in r (coalesced 128B)
    #pragma unroll
    for (int it = 0; it < 32; ++it) {
        int r = tid & 31;
        int d = (tid >> 5) + it * 8;
        Xl[r * 260 + d] = Xb[(size_t)d * NT + r];
    }
    __syncthreads();

    const int rg = tid & 7;
    const int kg = tid >> 3;

    double best[4];
    int    bidx[4];
    #pragma unroll
    for (int j = 0; j < 4; ++j) { best[j] = 1e300; bidx[j] = 0; }

    for (int kp = 0; kp < 8; ++kp) {
        const int kbase = kp * 128 + kg * 4;
        double acc[4][4];
        #pragma unroll
        for (int j = 0; j < 4; ++j)
            #pragma unroll
            for (int kk = 0; kk < 4; ++kk) acc[j][kk] = 0.0;

        for (int d = 0; d < 256; d += 4) {
            float4 xv[4], ev[4];
            #pragma unroll
            for (int j = 0; j < 4; ++j)
                xv[j] = *(const float4*)&Xl[(rg + 8 * j) * 260 + d];
            #pragma unroll
            for (int kk = 0; kk < 4; ++kk)
                ev[kk] = E4[(size_t)(kbase + kk) * 64 + (d >> 2)];
            #pragma unroll
            for (int j = 0; j < 4; ++j)
                #pragma unroll
                for (int kk = 0; kk < 4; ++kk) {
                    acc[j][kk] += (double)xv[j].x * (double)ev[kk].x
                                + (double)xv[j].y * (double)ev[kk].y
                                + (double)xv[j].z * (double)ev[kk].z
                                + (double)xv[j].w * (double)ev[kk].w;
                }
        }

        #pragma unroll
        for (int kk = 0; kk < 4; ++kk) {
            double e2k = e2[kbase + kk];
            #pragma unroll
            for (int j = 0; j < 4; ++j) {
                double s = e2k - 2.0 * acc[j][kk];
                if (s < best[j]) { best[j] = s; bidx[j] = kbase + kk; }  // k ascending per thread
            }
        }
    }

    #pragma unroll
    for (int j = 0; j < 4; ++j) {
        sm_m[rg + 8 * j][kg] = best[j];
        sm_i[rg + 8 * j][kg] = bidx[j];
    }
    __syncthreads();

    if (tid < 32) {
        double bm = 1e300; int bi = 0x7fffffff;
        for (int g = 0; g < 32; ++g) {
            double m = sm_m[tid][g];
            int    i = sm_i[tid][g];
            if (m < bm || (m == bm && i < bi)) { bm = m; bi = i; }  // numpy argmin: first index wins
        }
        idx_ws[n0 + tid] = bi;
        out[IDX_OFF + n0 + tid] = (float)bi;
    }
}

// ---------------- Kernel B: gather quantized, straight-through output, fused MSE accumulate
// Grid: B*D blocks; threads over t (coalesced in t).
__global__ __launch_bounds__(256) void vq_gather(const float* __restrict__ X,
                                                 const float* __restrict__ E,
                                                 const int* __restrict__ idx_ws,
                                                 float* __restrict__ out,
                                                 double* __restrict__ accum) {
    const int bd = blockIdx.x;
    const int d  = bd & (ND - 1);
    const int b  = bd >> 8;
    const float* xrow = X   + (size_t)bd * NT;
    float*       orow = out + (size_t)bd * NT;
    const int*   irow = idx_ws + b * NT;

    double ls = 0.0;
    #pragma unroll
    for (int i = 0; i < 8; ++i) {
        int t = threadIdx.x + i * 256;
        int id = irow[t];
        float q = E[(size_t)id * ND + d];   // gather (L2-hot, E = 1MB)
        float x = xrow[t];
        orow[t] = x + (q - x);              // straight-through, same rounding as reference
        double df = (double)q - (double)x;
        ls += df * df;
    }
    #pragma unroll
    for (int off = 32; off; off >>= 1) ls += __shfl_down(ls, off, 64);
    if ((threadIdx.x & 63) == 0) atomicAdd(accum, ls);
}

// ---------------- Kernel C: finalize scalars
__global__ void vq_final(const double* __restrict__ accum, float* __restrict__ out) {
    double mse = accum[0] * (1.0 / (double)QSIZE);
    out[SCL_OFF + 0] = (float)(1.25 * mse);  // loss = q_latent + 0.25 * e_latent
    out[SCL_OFF + 1] = (float)mse;           // e_latent_loss
    out[SCL_OFF + 2] = (float)mse;           // q_latent_loss (== e_latent in forward)
}

extern "C" void kernel_launch(void* const* d_in, const int* in_sizes, int n_in,
                              void* d_out, int out_size, void* d_ws, size_t ws_size,
                              hipStream_t stream) {
    const float* X = (const float*)d_in[0];        // [16, 256, 2048]
    const float* E = (const float*)d_in[1];        // [1024, 256]
    float* out = (float*)d_out;

    double* accum = (double*)d_ws;                                  // 8 B
    double* e2    = (double*)((char*)d_ws + 64);                    // 8 KB
    int*    idxws = (int*)   ((char*)d_ws + 64 + 8192);             // 128 KB

    vq_e2<<<NK, 64, 0, stream>>>((const float4*)E, e2, accum);
    vq_argmin<<<NN / 32, 256, 0, stream>>>(X, (const float4*)E, e2, idxws, out);
    vq_gather<<<NB * ND, 256, 0, stream>>>(X, E, idxws, out, accum);
    vq_final<<<1, 1, 0, stream>>>(accum, out);
}

// Round 2
// 661.635 us; speedup vs baseline: 1.1275x; 1.1275x over previous
//
#include <hip/hip_runtime.h>
#include <hip/hip_bf16.h>

// VectorQuantizer: B=16, D=256, T=2048, K=1024, N=B*T=32768
// inputs: [B, D, T] fp32 ; embeddings: [K, D] fp32
// outputs (concat, fp32): quantized_st [B,D,T] | loss | e_latent | q_latent | indices [32768]
#define NB 16
#define ND 256
#define NT 2048
#define NK 1024
#define NN (NB * NT)
#define QSIZE (NB * ND * NT)
#define SCL_OFF QSIZE
#define IDX_OFF (QSIZE + 3)
#define TAU 2.0e-4f   // fp32 score error bound ~6.5e-6; 30x headroom; ~500 rows refined

// ws layout (bytes)
#define WS_ACCUM 0        // double
#define WS_CNT   8        // int
#define WS_E2F   1024     // float[1024]
#define WS_E2D   8192     // double[1024]
#define WS_IDX   16384    // int[32768]
#define WS_LIST  147456   // int[32768]

// ---------------- Kernel 0: e2[k] (fp64 + fp32 copy); zero accum + refine counter
__global__ __launch_bounds__(64) void vq_e2(const float4* __restrict__ E4,
                                            double* __restrict__ e2d,
                                            float* __restrict__ e2f,
                                            double* __restrict__ accum,
                                            int* __restrict__ cnt) {
    int k = blockIdx.x;
    int lane = threadIdx.x;
    float4 v = E4[k * 64 + lane];
    double s = (double)v.x * v.x + (double)v.y * v.y + (double)v.z * v.z + (double)v.w * v.w;
    #pragma unroll
    for (int off = 32; off; off >>= 1) s += __shfl_down(s, off, 64);
    if (lane == 0) { e2d[k] = s; e2f[k] = (float)s; }
    if (k == 0 && lane == 0) { accum[0] = 0.0; cnt[0] = 0; }
}

// ---------------- Pass 1: fp32 argmin with second-best margin tracking
// Block: 256 threads, 32 rows. Thread (rg=tid&7, kg=tid>>3): rows {rg+8j}, k = kp*128+kg*4+kk.
__global__ __launch_bounds__(256) void vq_pass1(const float* __restrict__ X,
                                                const float4* __restrict__ E4,
                                                const float* __restrict__ e2f,
                                                int* __restrict__ idx_ws,
                                                int* __restrict__ cnt,
                                                int* __restrict__ list,
                                                float* __restrict__ out) {
    __shared__ float Xl[32 * 260];       // stride 260: conflict-free b128 reads at row-stride 8
    __shared__ float sm_m1[32][32];
    __shared__ float sm_m2[32][32];
    __shared__ int   sm_i [32][32];

    const int tid = threadIdx.x;
    const int n0  = blockIdx.x * 32;
    const int b   = n0 >> 11;
    const int t0  = n0 & (NT - 1);
    const float* Xb = X + (size_t)b * (ND * NT) + t0;

    #pragma unroll
    for (int it = 0; it < 32; ++it) {
        int r = tid & 31;
        int d = (tid >> 5) + it * 8;
        Xl[r * 260 + d] = Xb[(size_t)d * NT + r];
    }
    __syncthreads();

    const int rg = tid & 7;
    const int kg = tid >> 3;

    float b1[4], b2[4];
    int   i1[4];
    #pragma unroll
    for (int j = 0; j < 4; ++j) { b1[j] = 3e38f; b2[j] = 3e38f; i1[j] = 0; }

    const float* xr[4];
    #pragma unroll
    for (int j = 0; j < 4; ++j) xr[j] = &Xl[(rg + 8 * j) * 260];

    for (int kp = 0; kp < 8; ++kp) {
        const int kbase = kp * 128 + kg * 4;
        const float4* e0 = E4 + (size_t)(kbase + 0) * 64;
        const float4* e1 = E4 + (size_t)(kbase + 1) * 64;
        const float4* e2 = E4 + (size_t)(kbase + 2) * 64;
        const float4* e3 = E4 + (size_t)(kbase + 3) * 64;

        float acc[4][4];
        #pragma unroll
        for (int j = 0; j < 4; ++j)
            #pragma unroll
            for (int kk = 0; kk < 4; ++kk) acc[j][kk] = 0.0f;

        #pragma unroll 4
        for (int dq = 0; dq < 64; ++dq) {
            float4 xv[4], ev[4];
            #pragma unroll
            for (int j = 0; j < 4; ++j) xv[j] = *(const float4*)&xr[j][dq * 4];
            ev[0] = e0[dq]; ev[1] = e1[dq]; ev[2] = e2[dq]; ev[3] = e3[dq];
            #pragma unroll
            for (int j = 0; j < 4; ++j)
                #pragma unroll
                for (int kk = 0; kk < 4; ++kk) {
                    acc[j][kk] += xv[j].x * ev[kk].x + xv[j].y * ev[kk].y
                                + xv[j].z * ev[kk].z + xv[j].w * ev[kk].w;
                }
        }

        #pragma unroll
        for (int kk = 0; kk < 4; ++kk) {
            float e2k = e2f[kbase + kk];
            #pragma unroll
            for (int j = 0; j < 4; ++j) {
                float s = e2k - 2.0f * acc[j][kk];
                if (s < b1[j]) { b2[j] = b1[j]; b1[j] = s; i1[j] = kbase + kk; }
                else if (s < b2[j]) { b2[j] = s; }
            }
        }
    }

    #pragma unroll
    for (int j = 0; j < 4; ++j) {
        sm_m1[rg + 8 * j][kg] = b1[j];
        sm_m2[rg + 8 * j][kg] = b2[j];
        sm_i [rg + 8 * j][kg] = i1[j];
    }
    __syncthreads();

    if (tid < 32) {
        float B1 = 3e38f, B2 = 3e38f;
        int   I1 = 0x7fffffff;
        for (int g = 0; g < 32; ++g) {
            float m1 = sm_m1[tid][g];
            float m2 = sm_m2[tid][g];
            int   ig = sm_i [tid][g];
            if (m1 < B1 || (m1 == B1 && ig < I1)) {
                B2 = fminf(B1, m2);           // old best becomes second candidate
                B1 = m1; I1 = ig;
            } else {
                B2 = fminf(B2, m1);
            }
        }
        int n = n0 + tid;
        idx_ws[n] = I1;
        out[IDX_OFF + n] = (float)I1;
        if (B2 - B1 < TAU) {                  // ambiguous in fp32 -> exact refine
            int p = atomicAdd(cnt, 1);
            list[p] = n;
        }
    }
}

// ---------------- Refine: exact fp64 argmin for flagged rows (expected ~500)
__global__ __launch_bounds__(256) void vq_refine(const float* __restrict__ X,
                                                 const float4* __restrict__ E4,
                                                 const double* __restrict__ e2d,
                                                 const int* __restrict__ cnt,
                                                 const int* __restrict__ list,
                                                 int* __restrict__ idx_ws,
                                                 float* __restrict__ out) {
    __shared__ double xs[256];
    __shared__ double sm_s[256];
    __shared__ int    sm_k[256];
    const int m = cnt[0];
    for (int j = blockIdx.x; j < m; j += gridDim.x) {
        const int n = list[j];
        const int b = n >> 11;
        const int t = n & (NT - 1);
        xs[threadIdx.x] = (double)X[((size_t)b * ND + threadIdx.x) * NT + t];
        __syncthreads();
        double bs = 1e300; int bk = 0;
        #pragma unroll
        for (int kk = 0; kk < 4; ++kk) {
            const int k = threadIdx.x * 4 + kk;
            const float4* ek = E4 + (size_t)k * 64;
            double acc = 0.0;
            for (int dq = 0; dq < 64; ++dq) {
                float4 e = ek[dq];
                acc += xs[dq * 4 + 0] * (double)e.x + xs[dq * 4 + 1] * (double)e.y
                     + xs[dq * 4 + 2] * (double)e.z + xs[dq * 4 + 3] * (double)e.w;
            }
            double s = e2d[k] - 2.0 * acc;
            if (s < bs) { bs = s; bk = k; }   // k ascending -> first-index tie-break
        }
        sm_s[threadIdx.x] = bs; sm_k[threadIdx.x] = bk;
        __syncthreads();
        if (threadIdx.x == 0) {
            double B = 1e300; int I = 0;
            for (int i = 0; i < 256; ++i)     // tid ascending = k ascending; strict < keeps first
                if (sm_s[i] < B) { B = sm_s[i]; I = sm_k[i]; }
            idx_ws[n] = I;
            out[IDX_OFF + n] = (float)I;
        }
        __syncthreads();
    }
}

// ---------------- Gather via LDS tile-transpose + fused MSE
// Block: 32 t-values of one b. Stage the 32 E rows (coalesced), write out coalesced.
__global__ __launch_bounds__(256) void vq_gather(const float* __restrict__ X,
                                                 const float4* __restrict__ E4,
                                                 const int* __restrict__ idx_ws,
                                                 float* __restrict__ out,
                                                 double* __restrict__ accum) {
    __shared__ float Eq[32 * 257];   // stride 257: read phase (tw+d)%32 -> 2-way (free)
    const int bt = blockIdx.x;       // grid = NB * (NT/32) = 1024
    const int b  = bt >> 6;
    const int t0 = (bt & 63) << 5;
    const int* irow = idx_ws + b * NT + t0;

    // stage: thread (r = tid>>3, l8 = tid&7): 8 float4 per thread, coalesced 128B/row
    {
        const int r  = threadIdx.x >> 3;
        const int l8 = threadIdx.x & 7;
        const int id = irow[r];
        const float4* er = E4 + (size_t)id * 64;
        #pragma unroll
        for (int it = 0; it < 8; ++it) {
            int c = l8 + (it << 3);
            float4 v = er[c];
            float* p = &Eq[r * 257 + 4 * c];
            p[0] = v.x; p[1] = v.y; p[2] = v.z; p[3] = v.w;   // 2-way bank alias: free
        }
    }
    __syncthreads();

    // write: thread (tw = tid&31, dg = tid>>5): d = dg + 8*it; coalesced X read + out write
    const int tw = threadIdx.x & 31;
    const int dg = threadIdx.x >> 5;
    double ls = 0.0;
    #pragma unroll 8
    for (int it = 0; it < 32; ++it) {
        const int d = dg + (it << 3);
        const float q = Eq[tw * 257 + d];
        const size_t off = ((size_t)b * ND + d) * NT + t0 + tw;
        const float x = X[off];
        out[off] = x + (q - x);              // straight-through, same rounding as reference
        const double df = (double)q - (double)x;
        ls = fma(df, df, ls);
    }
    #pragma unroll
    for (int o = 32; o; o >>= 1) ls += __shfl_down(ls, o, 64);
    if ((threadIdx.x & 63) == 0) atomicAdd(accum, ls);
}

// ---------------- Finalize scalars
__global__ void vq_final(const double* __restrict__ accum, float* __restrict__ out) {
    double mse = accum[0] * (1.0 / (double)QSIZE);
    out[SCL_OFF + 0] = (float)(1.25 * mse);  // loss = q_latent + 0.25*e_latent
    out[SCL_OFF + 1] = (float)mse;
    out[SCL_OFF + 2] = (float)mse;
}

extern "C" void kernel_launch(void* const* d_in, const int* in_sizes, int n_in,
                              void* d_out, int out_size, void* d_ws, size_t ws_size,
                              hipStream_t stream) {
    const float* X = (const float*)d_in[0];   // [16, 256, 2048]
    const float* E = (const float*)d_in[1];   // [1024, 256]
    float* out = (float*)d_out;

    char* ws = (char*)d_ws;
    double* accum = (double*)(ws + WS_ACCUM);
    int*    cnt   = (int*)   (ws + WS_CNT);
    float*  e2f   = (float*) (ws + WS_E2F);
    double* e2d   = (double*)(ws + WS_E2D);
    int*    idxws = (int*)   (ws + WS_IDX);
    int*    list  = (int*)   (ws + WS_LIST);

    vq_e2    <<<NK, 64, 0, stream>>>((const float4*)E, e2d, e2f, accum, cnt);
    vq_pass1 <<<NN / 32, 256, 0, stream>>>(X, (const float4*)E, e2f, idxws, cnt, list, out);
    vq_refine<<<256, 256, 0, stream>>>(X, (const float4*)E, e2d, cnt, list, idxws, out);
    vq_gather<<<NB * (NT / 32), 256, 0, stream>>>(X, (const float4*)E, idxws, out, accum);
    vq_final <<<1, 1, 0, stream>>>(accum, out);
}

// Round 3
// 308.368 us; speedup vs baseline: 2.4191x; 2.1456x over previous
//
#include <hip/hip_runtime.h>
#include <hip/hip_bf16.h>

// VectorQuantizer: B=16, D=256, T=2048, K=1024, N=B*T=32768
// inputs: [B, D, T] fp32 ; embeddings: [K, D] fp32
// outputs (concat, fp32): quantized_st [B,D,T] | loss | e_latent | q_latent | indices [32768]
#define NB 16
#define ND 256
#define NT 2048
#define NK 1024
#define NN (NB * NT)
#define QSIZE (NB * ND * NT)
#define SCL_OFF QSIZE
#define IDX_OFF (QSIZE + 3)
// bf16-split score error bound (Cauchy-Schwarz, ||x||<=20, ||e||<=0.0101): ~1e-5/score worst.
// TAU = 4e-5 -> m ~ 2300 rows refined (margin ~ Exp(6.2e-4), measured round 2 via WRITE_SIZE).
#define TAU 4.0e-5f

// ws layout (bytes)
#define WS_ACCUM 0        // double
#define WS_CNT   8        // int
#define WS_E2F   1024     // float[1024]
#define WS_E2D   8192     // double[1024]
#define WS_IDX   16384    // int[32768]
#define WS_LIST  147456   // int[32768]
#define WS_BPACK 278528   // ushort[64][2][8][64][8] bf16 = 2 MB (B-fragment-packed E, hi|lo)

typedef __attribute__((ext_vector_type(8))) short bf16x8;
typedef __attribute__((ext_vector_type(4))) float f32x4;
#define MFMA16(a, b, c) __builtin_amdgcn_mfma_f32_16x16x32_bf16(a, b, c, 0, 0, 0)

__device__ inline void bf16split(float v, short& hi, short& lo) {
    union { __hip_bfloat16 b; short s; } uh, ul;
    uh.b = __float2bfloat16(v);
    float hf = __bfloat162float(uh.b);
    ul.b = __float2bfloat16(v - hf);
    hi = uh.s; lo = ul.s;
}

// ---------------- e2[k] (fp64 + fp32); zero accum + refine counter
__global__ __launch_bounds__(64) void vq_e2(const float4* __restrict__ E4,
                                            double* __restrict__ e2d,
                                            float* __restrict__ e2f,
                                            double* __restrict__ accum,
                                            int* __restrict__ cnt) {
    int k = blockIdx.x;
    int lane = threadIdx.x;
    float4 v = E4[k * 64 + lane];
    double s = (double)v.x * v.x + (double)v.y * v.y + (double)v.z * v.z + (double)v.w * v.w;
    #pragma unroll
    for (int off = 32; off; off >>= 1) s += __shfl_down(s, off, 64);
    if (lane == 0) { e2d[k] = s; e2f[k] = (float)s; }
    if (k == 0 && lane == 0) { accum[0] = 0.0; cnt[0] = 0; }
}

// ---------------- Pack E into MFMA B-fragment layout, bf16 hi/lo split.
// Bpack[cc][split][ds][lane][j]: code c = cc*16 + (lane&15), d = ds*32 + (lane>>4)*8 + j.
__global__ __launch_bounds__(64) void vq_prep_bpack(const float4* __restrict__ E4,
                                                    uint4* __restrict__ Bp4) {
    const int cc = blockIdx.x >> 3;
    const int ds = blockIdx.x & 7;
    const int lane = threadIdx.x;
    const int c = cc * 16 + (lane & 15);
    const int q = lane >> 4;
    float4 v0 = E4[(size_t)c * 64 + ds * 8 + q * 2];
    float4 v1 = E4[(size_t)c * 64 + ds * 8 + q * 2 + 1];
    float vals[8] = {v0.x, v0.y, v0.z, v0.w, v1.x, v1.y, v1.z, v1.w};
    union { short s[8]; uint4 v; } hi, lo;
    #pragma unroll
    for (int j = 0; j < 8; ++j) bf16split(vals[j], hi.s[j], lo.s[j]);
    Bp4[(size_t)cc * 1024 + ds * 64 + lane]       = hi.v;   // split 0
    Bp4[(size_t)cc * 1024 + 512 + ds * 64 + lane] = lo.v;   // split 1
}

// ---------------- Pass 1: MFMA bf16x3-split distance GEMM + per-row argmin (b1/b2 margin)
// Block = 256 thr = 4 waves; wave = 2 row-tiles of 16 (32 rows); block = 128 rows.
// A-frags (X) in registers across the whole code loop; B chunk (16 codes) staged in LDS.
__global__ __launch_bounds__(256, 1) void vq_pass1(const float* __restrict__ X,
                                                   const uint4* __restrict__ Bp4,
                                                   const float* __restrict__ e2f,
                                                   int* __restrict__ idx_ws,
                                                   int* __restrict__ cnt,
                                                   int* __restrict__ list,
                                                   float* __restrict__ out) {
    __shared__ uint4 Bl4[1024];   // 16 KB: one chunk = [split][ds][lane][j]
    const int tid  = threadIdx.x;
    const int lane = tid & 63;
    const int w    = tid >> 6;
    const int n0   = blockIdx.x * 128;
    const int b    = n0 >> 11;
    const int t0   = n0 & (NT - 1);
    const int m16  = lane & 15;
    const int q    = lane >> 4;

    // Build A fragments: lane holds A[m=lane&15][k=q*8+j] for d = ds*32 + q*8 + j.
    bf16x8 ah[2][8], al[2][8];
    const float* Xb = X + (size_t)b * (ND * NT);
    #pragma unroll
    for (int t = 0; t < 2; ++t) {
        const int trow = t0 + w * 32 + t * 16 + m16;
        #pragma unroll
        for (int ds = 0; ds < 8; ++ds) {
            #pragma unroll
            for (int j = 0; j < 8; ++j) {
                const int d = ds * 32 + q * 8 + j;
                float v = Xb[(size_t)d * NT + trow];
                short h, l; bf16split(v, h, l);
                ah[t][ds][j] = h; al[t][ds][j] = l;
            }
        }
    }

    float b1[2][4], b2[2][4]; int i1[2][4];
    #pragma unroll
    for (int t = 0; t < 2; ++t)
        #pragma unroll
        for (int r = 0; r < 4; ++r) { b1[t][r] = 3e38f; b2[t][r] = 3e38f; i1[t][r] = 0; }

    // stage chunk 0
    uint4 pre[4];
    #pragma unroll
    for (int i = 0; i < 4; ++i) pre[i] = Bp4[tid + 256 * i];
    #pragma unroll
    for (int i = 0; i < 4; ++i) Bl4[tid + 256 * i] = pre[i];
    __syncthreads();

    for (int cc = 0; cc < 64; ++cc) {
        if (cc < 63) {
            #pragma unroll
            for (int i = 0; i < 4; ++i) pre[i] = Bp4[(size_t)(cc + 1) * 1024 + tid + 256 * i];
        }
        f32x4 acc0 = {0.f, 0.f, 0.f, 0.f};
        f32x4 acc1 = {0.f, 0.f, 0.f, 0.f};
        const bf16x8* Bf = (const bf16x8*)Bl4;
        #pragma unroll
        for (int ds = 0; ds < 8; ++ds) {
            bf16x8 bh = Bf[ds * 64 + lane];
            bf16x8 bl = Bf[512 + ds * 64 + lane];
            acc0 = MFMA16(ah[0][ds], bh, acc0);   // xh.eh
            acc0 = MFMA16(al[0][ds], bh, acc0);   // xl.eh
            acc0 = MFMA16(ah[0][ds], bl, acc0);   // xh.el
            acc1 = MFMA16(ah[1][ds], bh, acc1);
            acc1 = MFMA16(al[1][ds], bh, acc1);
            acc1 = MFMA16(ah[1][ds], bl, acc1);
        }
        const float e2v = e2f[cc * 16 + m16];
        const int  code = cc * 16 + m16;
        #pragma unroll
        for (int r = 0; r < 4; ++r) {
            float s0 = e2v - 2.0f * acc0[r];
            if (s0 < b1[0][r]) { b2[0][r] = b1[0][r]; b1[0][r] = s0; i1[0][r] = code; }
            else if (s0 < b2[0][r]) b2[0][r] = s0;
            float s1 = e2v - 2.0f * acc1[r];
            if (s1 < b1[1][r]) { b2[1][r] = b1[1][r]; b1[1][r] = s1; i1[1][r] = code; }
            else if (s1 < b2[1][r]) b2[1][r] = s1;
        }
        __syncthreads();                       // all waves done reading Bl4
        if (cc < 63) {
            #pragma unroll
            for (int i = 0; i < 4; ++i) Bl4[tid + 256 * i] = pre[i];
            __syncthreads();                   // next chunk visible
        }
    }

    // Reduce across the 16 code-classes (lanes within each 16-group share rows).
    #pragma unroll
    for (int t = 0; t < 2; ++t) {
        #pragma unroll
        for (int r = 0; r < 4; ++r) {
            float B1 = b1[t][r], B2 = b2[t][r]; int I1 = i1[t][r];
            #pragma unroll
            for (int mm = 1; mm < 16; mm <<= 1) {
                float o1 = __shfl_xor(B1, mm, 16);
                float o2 = __shfl_xor(B2, mm, 16);
                int   oi = __shfl_xor(I1, mm, 16);
                if (o1 < B1 || (o1 == B1 && oi < I1)) { B2 = fminf(B1, o2); B1 = o1; I1 = oi; }
                else B2 = fminf(B2, o1);
            }
            if (m16 == 0) {
                int n = n0 + w * 32 + t * 16 + q * 4 + r;   // C/D: row = quad*4 + reg
                idx_ws[n] = I1;
                out[IDX_OFF + n] = (float)I1;
                if (B2 - B1 < TAU) { int p = atomicAdd(cnt, 1); list[p] = n; }
            }
        }
    }
}

// ---------------- Refine: exact fp64 argmin for flagged rows; 4 rows/pass share E reads.
__global__ __launch_bounds__(256, 2) void vq_refine(const float* __restrict__ X,
                                                    const float4* __restrict__ E4,
                                                    const double* __restrict__ e2d,
                                                    const int* __restrict__ cnt,
                                                    const int* __restrict__ list,
                                                    int* __restrict__ idx_ws,
                                                    float* __restrict__ out) {
    __shared__ double xs[4][256];
    __shared__ double sm_s[4][4];
    __shared__ int    sm_k[4][4];
    const int m = cnt[0];
    const int tid = threadIdx.x;
    for (int p = blockIdx.x; p * 4 < m; p += 512) {
        int nrow[4];
        #pragma unroll
        for (int g = 0; g < 4; ++g) {
            int j = p * 4 + g;
            nrow[g] = list[j < m ? j : m - 1];
        }
        #pragma unroll
        for (int g = 0; g < 4; ++g) {
            int n = nrow[g]; int bb = n >> 11; int tt = n & (NT - 1);
            xs[g][tid] = (double)X[((size_t)bb * ND + tid) * NT + tt];
        }
        __syncthreads();
        double acc[4][4];   // [kk][g]
        #pragma unroll
        for (int kk = 0; kk < 4; ++kk)
            #pragma unroll
            for (int g = 0; g < 4; ++g) acc[kk][g] = 0.0;
        for (int dq = 0; dq < 64; ++dq) {
            double xv[4][4];
            #pragma unroll
            for (int g = 0; g < 4; ++g)
                #pragma unroll
                for (int c = 0; c < 4; ++c) xv[g][c] = xs[g][dq * 4 + c];   // broadcast reads
            #pragma unroll
            for (int kk = 0; kk < 4; ++kk) {
                float4 ev = E4[(size_t)(kk * 256 + tid) * 64 + dq];
                double e0 = ev.x, e1 = ev.y, e2 = ev.z, e3 = ev.w;
                #pragma unroll
                for (int g = 0; g < 4; ++g)
                    acc[kk][g] += xv[g][0] * e0 + xv[g][1] * e1 + xv[g][2] * e2 + xv[g][3] * e3;
            }
        }
        #pragma unroll
        for (int g = 0; g < 4; ++g) {
            double bs = 1e300; int bk = 0x7fffffff;
            #pragma unroll
            for (int kk = 0; kk < 4; ++kk) {
                int k = kk * 256 + tid;
                double s = e2d[k] - 2.0 * acc[kk][g];
                if (s < bs) { bs = s; bk = k; }   // kk ascending: first-index wins
            }
            #pragma unroll
            for (int mm = 1; mm < 64; mm <<= 1) {
                double os = __shfl_xor(bs, mm, 64);
                int    ok = __shfl_xor(bk, mm, 64);
                if (os < bs || (os == bs && ok < bk)) { bs = os; bk = ok; }
            }
            if ((tid & 63) == 0) { sm_s[tid >> 6][g] = bs; sm_k[tid >> 6][g] = bk; }
        }
        __syncthreads();
        if (tid < 4) {   // tid = g
            double Bv = 1e300; int Kv = 0x7fffffff;
            for (int ww = 0; ww < 4; ++ww) {
                double s2 = sm_s[ww][tid]; int k2 = sm_k[ww][tid];
                if (s2 < Bv || (s2 == Bv && k2 < Kv)) { Bv = s2; Kv = k2; }
            }
            if (p * 4 + tid < m) {
                int n = nrow[tid];
                idx_ws[n] = Kv;
                out[IDX_OFF + n] = (float)Kv;
            }
        }
        __syncthreads();
    }
}

// ---------------- Gather via LDS tile-transpose + fused MSE (unchanged from round 2)
__global__ __launch_bounds__(256) void vq_gather(const float* __restrict__ X,
                                                 const float4* __restrict__ E4,
                                                 const int* __restrict__ idx_ws,
                                                 float* __restrict__ out,
                                                 double* __restrict__ accum) {
    __shared__ float Eq[32 * 257];
    const int bt = blockIdx.x;
    const int b  = bt >> 6;
    const int t0 = (bt & 63) << 5;
    const int* irow = idx_ws + b * NT + t0;
    {
        const int r  = threadIdx.x >> 3;
        const int l8 = threadIdx.x & 7;
        const int id = irow[r];
        const float4* er = E4 + (size_t)id * 64;
        #pragma unroll
        for (int it = 0; it < 8; ++it) {
            int c = l8 + (it << 3);
            float4 v = er[c];
            float* p = &Eq[r * 257 + 4 * c];
            p[0] = v.x; p[1] = v.y; p[2] = v.z; p[3] = v.w;
        }
    }
    __syncthreads();
    const int tw = threadIdx.x & 31;
    const int dg = threadIdx.x >> 5;
    double ls = 0.0;
    #pragma unroll 8
    for (int it = 0; it < 32; ++it) {
        const int d = dg + (it << 3);
        const float qv = Eq[tw * 257 + d];
        const size_t off = ((size_t)b * ND + d) * NT + t0 + tw;
        const float x = X[off];
        out[off] = x + (qv - x);
        const double df = (double)qv - (double)x;
        ls = fma(df, df, ls);
    }
    #pragma unroll
    for (int o = 32; o; o >>= 1) ls += __shfl_down(ls, o, 64);
    if ((threadIdx.x & 63) == 0) atomicAdd(accum, ls);
}

// ---------------- Finalize scalars
__global__ void vq_final(const double* __restrict__ accum, float* __restrict__ out) {
    double mse = accum[0] * (1.0 / (double)QSIZE);
    out[SCL_OFF + 0] = (float)(1.25 * mse);
    out[SCL_OFF + 1] = (float)mse;
    out[SCL_OFF + 2] = (float)mse;
}

extern "C" void kernel_launch(void* const* d_in, const int* in_sizes, int n_in,
                              void* d_out, int out_size, void* d_ws, size_t ws_size,
                              hipStream_t stream) {
    const float* X = (const float*)d_in[0];   // [16, 256, 2048]
    const float* E = (const float*)d_in[1];   // [1024, 256]
    float* out = (float*)d_out;

    char* ws = (char*)d_ws;
    double* accum = (double*)(ws + WS_ACCUM);
    int*    cnt   = (int*)   (ws + WS_CNT);
    float*  e2f   = (float*) (ws + WS_E2F);
    double* e2d   = (double*)(ws + WS_E2D);
    int*    idxws = (int*)   (ws + WS_IDX);
    int*    list  = (int*)   (ws + WS_LIST);
    uint4*  bpack = (uint4*) (ws + WS_BPACK);

    vq_e2        <<<NK, 64, 0, stream>>>((const float4*)E, e2d, e2f, accum, cnt);
    vq_prep_bpack<<<512, 64, 0, stream>>>((const float4*)E, bpack);
    vq_pass1     <<<NN / 128, 256, 0, stream>>>(X, bpack, e2f, idxws, cnt, list, out);
    vq_refine    <<<512, 256, 0, stream>>>(X, (const float4*)E, e2d, cnt, list, idxws, out);
    vq_gather    <<<NB * (NT / 32), 256, 0, stream>>>(X, (const float4*)E, idxws, out, accum);
    vq_final     <<<1, 1, 0, stream>>>(accum, out);
}

// Round 4
// 235.772 us; speedup vs baseline: 3.1640x; 1.3079x over previous
//
#include <hip/hip_runtime.h>
#include <hip/hip_bf16.h>

// VectorQuantizer: B=16, D=256, T=2048, K=1024, N=B*T=32768
// inputs: [B, D, T] fp32 ; embeddings: [K, D] fp32
// outputs (concat, fp32): quantized_st [B,D,T] | loss | e_latent | q_latent | indices [32768]
#define NB 16
#define ND 256
#define NT 2048
#define NK 1024
#define NN (NB * NT)
#define QSIZE (NB * ND * NT)
#define SCL_OFF QSIZE
#define IDX_OFF (QSIZE + 3)
// bf16-split score error bound ~1e-5 worst; TAU=4e-5 -> ~2100 rows refined in exact fp64.
#define TAU 4.0e-5f

// ws layout (bytes)
#define WS_CNT   8        // int
#define WS_E2F   1024     // float[1024]
#define WS_E2D   8192     // double[1024]
#define WS_IDX   16384    // int[32768]
#define WS_LIST  147456   // int[32768]
#define WS_BPACK 278528   // 1 MB: B-fragment-packed E, bf16 hi|lo
#define WS_PART  1327104  // double[1024] per-block MSE partials

typedef __attribute__((ext_vector_type(8))) short bf16x8;
typedef __attribute__((ext_vector_type(4))) float f32x4;
#define MFMA16(a, b, c) __builtin_amdgcn_mfma_f32_16x16x32_bf16(a, b, c, 0, 0, 0)

__device__ inline void bf16split(float v, short& hi, short& lo) {
    union { __hip_bfloat16 b; short s; } uh, ul;
    uh.b = __float2bfloat16(v);
    float hf = __bfloat162float(uh.b);
    ul.b = __float2bfloat16(v - hf);
    hi = uh.s; lo = ul.s;
}

// ---------------- e2[k] (fp64 + fp32); zero refine counter
__global__ __launch_bounds__(64) void vq_e2(const float4* __restrict__ E4,
                                            double* __restrict__ e2d,
                                            float* __restrict__ e2f,
                                            int* __restrict__ cnt) {
    int k = blockIdx.x;
    int lane = threadIdx.x;
    float4 v = E4[k * 64 + lane];
    double s = (double)v.x * v.x + (double)v.y * v.y + (double)v.z * v.z + (double)v.w * v.w;
    #pragma unroll
    for (int off = 32; off; off >>= 1) s += __shfl_down(s, off, 64);
    if (lane == 0) { e2d[k] = s; e2f[k] = (float)s; }
    if (k == 0 && lane == 0) cnt[0] = 0;
}

// ---------------- Pack E into MFMA B-fragment layout, bf16 hi/lo split.
// Bpack[cc][split][ds][lane][j]: code c = cc*16 + (lane&15), d = ds*32 + (lane>>4)*8 + j.
__global__ __launch_bounds__(64) void vq_prep_bpack(const float4* __restrict__ E4,
                                                    uint4* __restrict__ Bp4) {
    const int cc = blockIdx.x >> 3;
    const int ds = blockIdx.x & 7;
    const int lane = threadIdx.x;
    const int c = cc * 16 + (lane & 15);
    const int q = lane >> 4;
    float4 v0 = E4[(size_t)c * 64 + ds * 8 + q * 2];
    float4 v1 = E4[(size_t)c * 64 + ds * 8 + q * 2 + 1];
    float vals[8] = {v0.x, v0.y, v0.z, v0.w, v1.x, v1.y, v1.z, v1.w};
    union { short s[8]; uint4 v; } hi, lo;
    #pragma unroll
    for (int j = 0; j < 8; ++j) bf16split(vals[j], hi.s[j], lo.s[j]);
    Bp4[(size_t)cc * 1024 + ds * 64 + lane]       = hi.v;
    Bp4[(size_t)cc * 1024 + 512 + ds * 64 + lane] = lo.v;
}

// ---------------- Pass 1: MFMA bf16-split distance GEMM + per-row argmin (b1/b2 margin)
// 256 thr = 4 waves; wave = 2 row-tiles of 16 (32 rows); block = 128 rows; grid = 256.
// SIX independent MFMA chains (2 tiles x 3 split terms); double-buffered LDS, 1 barrier/chunk.
__global__ __launch_bounds__(256, 1) void vq_pass1(const float* __restrict__ X,
                                                   const uint4* __restrict__ Bp4,
                                                   const float* __restrict__ e2f,
                                                   int* __restrict__ idx_ws,
                                                   int* __restrict__ cnt,
                                                   int* __restrict__ list,
                                                   float* __restrict__ out) {
    __shared__ uint4 Bl4[2][1024];   // 32 KB double buffer, chunk = 16 codes
    const int tid  = threadIdx.x;
    const int lane = tid & 63;
    const int w    = tid >> 6;
    const int n0   = blockIdx.x * 128;
    const int b    = n0 >> 11;
    const int t0   = n0 & (NT - 1);
    const int m16  = lane & 15;
    const int q    = lane >> 4;

    // Build A fragments: lane holds A[m=lane&15][k=q*8+j] for d = ds*32 + q*8 + j.
    bf16x8 ah[2][8], al[2][8];
    const float* Xb = X + (size_t)b * (ND * NT);
    #pragma unroll
    for (int t = 0; t < 2; ++t) {
        const int trow = t0 + w * 32 + t * 16 + m16;
        #pragma unroll
        for (int ds = 0; ds < 8; ++ds) {
            #pragma unroll
            for (int j = 0; j < 8; ++j) {
                const int d = ds * 32 + q * 8 + j;
                float v = Xb[(size_t)d * NT + trow];
                short h, l; bf16split(v, h, l);
                ah[t][ds][j] = h; al[t][ds][j] = l;
            }
        }
    }

    float b1[2][4], b2[2][4]; int i1[2][4];
    #pragma unroll
    for (int t = 0; t < 2; ++t)
        #pragma unroll
        for (int r = 0; r < 4; ++r) { b1[t][r] = 3e38f; b2[t][r] = 3e38f; i1[t][r] = 0; }

    uint4 pre[4];
    #pragma unroll
    for (int i = 0; i < 4; ++i) pre[i] = Bp4[tid + 256 * i];
    #pragma unroll
    for (int i = 0; i < 4; ++i) Bl4[0][tid + 256 * i] = pre[i];
    __syncthreads();

    for (int cc = 0; cc < 64; ++cc) {
        const bf16x8* Bf = (const bf16x8*)Bl4[cc & 1];
        if (cc < 63) {
            #pragma unroll
            for (int i = 0; i < 4; ++i) pre[i] = Bp4[(size_t)(cc + 1) * 1024 + tid + 256 * i];
        }
        f32x4 hh0 = {0.f,0.f,0.f,0.f}, lh0 = {0.f,0.f,0.f,0.f}, hl0 = {0.f,0.f,0.f,0.f};
        f32x4 hh1 = {0.f,0.f,0.f,0.f}, lh1 = {0.f,0.f,0.f,0.f}, hl1 = {0.f,0.f,0.f,0.f};
        #pragma unroll
        for (int ds = 0; ds < 8; ++ds) {
            bf16x8 bh = Bf[ds * 64 + lane];
            bf16x8 bl = Bf[512 + ds * 64 + lane];
            hh0 = MFMA16(ah[0][ds], bh, hh0);   // 6 independent chains:
            hh1 = MFMA16(ah[1][ds], bh, hh1);   // dep distance 6 > MFMA latency
            lh0 = MFMA16(al[0][ds], bh, lh0);
            lh1 = MFMA16(al[1][ds], bh, lh1);
            hl0 = MFMA16(ah[0][ds], bl, hl0);
            hl1 = MFMA16(ah[1][ds], bl, hl1);
        }
        if (cc < 63) {
            #pragma unroll
            for (int i = 0; i < 4; ++i) Bl4[(cc + 1) & 1][tid + 256 * i] = pre[i];
            __syncthreads();   // readers of Bl4[cc&1] are done (lgkm drained by barrier)
        }
        const float e2v = e2f[cc * 16 + m16];
        const int  code = cc * 16 + m16;
        #pragma unroll
        for (int r = 0; r < 4; ++r) {
            float s0 = e2v - 2.0f * (hh0[r] + lh0[r] + hl0[r]);
            if (s0 < b1[0][r]) { b2[0][r] = b1[0][r]; b1[0][r] = s0; i1[0][r] = code; }
            else if (s0 < b2[0][r]) b2[0][r] = s0;
            float s1 = e2v - 2.0f * (hh1[r] + lh1[r] + hl1[r]);
            if (s1 < b1[1][r]) { b2[1][r] = b1[1][r]; b1[1][r] = s1; i1[1][r] = code; }
            else if (s1 < b2[1][r]) b2[1][r] = s1;
        }
    }

    // Reduce across the 16 code-classes (lanes within each 16-group share rows).
    #pragma unroll
    for (int t = 0; t < 2; ++t) {
        #pragma unroll
        for (int r = 0; r < 4; ++r) {
            float B1 = b1[t][r], B2 = b2[t][r]; int I1 = i1[t][r];
            #pragma unroll
            for (int mm = 1; mm < 16; mm <<= 1) {
                float o1 = __shfl_xor(B1, mm, 16);
                float o2 = __shfl_xor(B2, mm, 16);
                int   oi = __shfl_xor(I1, mm, 16);
                if (o1 < B1 || (o1 == B1 && oi < I1)) { B2 = fminf(B1, o2); B1 = o1; I1 = oi; }
                else B2 = fminf(B2, o1);
            }
            if (m16 == 0) {
                int n = n0 + w * 32 + t * 16 + q * 4 + r;   // C/D: row = quad*4 + reg
                idx_ws[n] = I1;
                out[IDX_OFF + n] = (float)I1;
                if (B2 - B1 < TAU) { int p = atomicAdd(cnt, 1); list[p] = n; }
            }
        }
    }
}

// ---------------- Refine: exact fp64 argmin for flagged rows; 4 rows/pass share E reads.
__global__ __launch_bounds__(256, 2) void vq_refine(const float* __restrict__ X,
                                                    const float4* __restrict__ E4,
                                                    const double* __restrict__ e2d,
                                                    const int* __restrict__ cnt,
                                                    const int* __restrict__ list,
                                                    int* __restrict__ idx_ws,
                                                    float* __restrict__ out) {
    __shared__ double xs[4][256];
    __shared__ double sm_s[4][4];
    __shared__ int    sm_k[4][4];
    const int m = cnt[0];
    const int tid = threadIdx.x;
    for (int p = blockIdx.x; p * 4 < m; p += 512) {
        int nrow[4];
        #pragma unroll
        for (int g = 0; g < 4; ++g) {
            int j = p * 4 + g;
            nrow[g] = list[j < m ? j : m - 1];
        }
        #pragma unroll
        for (int g = 0; g < 4; ++g) {
            int n = nrow[g]; int bb = n >> 11; int tt = n & (NT - 1);
            xs[g][tid] = (double)X[((size_t)bb * ND + tid) * NT + tt];
        }
        __syncthreads();
        double acc[4][4];   // [kk][g]
        #pragma unroll
        for (int kk = 0; kk < 4; ++kk)
            #pragma unroll
            for (int g = 0; g < 4; ++g) acc[kk][g] = 0.0;
        for (int dq = 0; dq < 64; ++dq) {
            double xv[4][4];
            #pragma unroll
            for (int g = 0; g < 4; ++g)
                #pragma unroll
                for (int c = 0; c < 4; ++c) xv[g][c] = xs[g][dq * 4 + c];
            #pragma unroll
            for (int kk = 0; kk < 4; ++kk) {
                float4 ev = E4[(size_t)(kk * 256 + tid) * 64 + dq];
                double e0 = ev.x, e1 = ev.y, e2 = ev.z, e3 = ev.w;
                #pragma unroll
                for (int g = 0; g < 4; ++g)
                    acc[kk][g] += xv[g][0] * e0 + xv[g][1] * e1 + xv[g][2] * e2 + xv[g][3] * e3;
            }
        }
        #pragma unroll
        for (int g = 0; g < 4; ++g) {
            double bs = 1e300; int bk = 0x7fffffff;
            #pragma unroll
            for (int kk = 0; kk < 4; ++kk) {
                int k = kk * 256 + tid;
                double s = e2d[k] - 2.0 * acc[kk][g];
                if (s < bs) { bs = s; bk = k; }
            }
            #pragma unroll
            for (int mm = 1; mm < 64; mm <<= 1) {
                double os = __shfl_xor(bs, mm, 64);
                int    ok = __shfl_xor(bk, mm, 64);
                if (os < bs || (os == bs && ok < bk)) { bs = os; bk = ok; }
            }
            if ((tid & 63) == 0) { sm_s[tid >> 6][g] = bs; sm_k[tid >> 6][g] = bk; }
        }
        __syncthreads();
        if (tid < 4) {
            double Bv = 1e300; int Kv = 0x7fffffff;
            for (int ww = 0; ww < 4; ++ww) {
                double s2 = sm_s[ww][tid]; int k2 = sm_k[ww][tid];
                if (s2 < Bv || (s2 == Bv && k2 < Kv)) { Bv = s2; Kv = k2; }
            }
            if (p * 4 + tid < m) {
                int n = nrow[tid];
                idx_ws[n] = Kv;
                out[IDX_OFF + n] = (float)Kv;
            }
        }
        __syncthreads();
    }
}

// ---------------- Gather via LDS tile-transpose + per-block MSE partial (NO global atomics)
__global__ __launch_bounds__(256) void vq_gather(const float* __restrict__ X,
                                                 const float4* __restrict__ E4,
                                                 const int* __restrict__ idx_ws,
                                                 float* __restrict__ out,
                                                 double* __restrict__ part) {
    __shared__ float Eq[32 * 257];
    __shared__ double sm[4];
    const int bt = blockIdx.x;
    const int b  = bt >> 6;
    const int t0 = (bt & 63) << 5;
    const int* irow = idx_ws + b * NT + t0;
    {
        const int r  = threadIdx.x >> 3;
        const int l8 = threadIdx.x & 7;
        const int id = irow[r];
        const float4* er = E4 + (size_t)id * 64;
        #pragma unroll
        for (int it = 0; it < 8; ++it) {
            int c = l8 + (it << 3);
            float4 v = er[c];
            float* p = &Eq[r * 257 + 4 * c];
            p[0] = v.x; p[1] = v.y; p[2] = v.z; p[3] = v.w;
        }
    }
    __syncthreads();
    const int tw = threadIdx.x & 31;
    const int dg = threadIdx.x >> 5;
    double ls = 0.0;
    #pragma unroll 8
    for (int it = 0; it < 32; ++it) {
        const int d = dg + (it << 3);
        const float qv = Eq[tw * 257 + d];
        const size_t off = ((size_t)b * ND + d) * NT + t0 + tw;
        const float x = X[off];
        out[off] = x + (qv - x);             // straight-through, reference rounding
        const double df = (double)qv - (double)x;
        ls = fma(df, df, ls);
    }
    #pragma unroll
    for (int o = 32; o; o >>= 1) ls += __shfl_down(ls, o, 64);
    if ((threadIdx.x & 63) == 0) sm[threadIdx.x >> 6] = ls;
    __syncthreads();
    if (threadIdx.x == 0) part[bt] = sm[0] + sm[1] + sm[2] + sm[3];
}

// ---------------- Finalize: reduce 1024 partials, write scalars
__global__ __launch_bounds__(256) void vq_final(const double* __restrict__ part,
                                                float* __restrict__ out) {
    __shared__ double sm[4];
    const int tid = threadIdx.x;
    double s = part[tid] + part[tid + 256] + part[tid + 512] + part[tid + 768];
    #pragma unroll
    for (int o = 32; o; o >>= 1) s += __shfl_down(s, o, 64);
    if ((tid & 63) == 0) sm[tid >> 6] = s;
    __syncthreads();
    if (tid == 0) {
        double mse = (sm[0] + sm[1] + sm[2] + sm[3]) * (1.0 / (double)QSIZE);
        out[SCL_OFF + 0] = (float)(1.25 * mse);
        out[SCL_OFF + 1] = (float)mse;
        out[SCL_OFF + 2] = (float)mse;
    }
}

extern "C" void kernel_launch(void* const* d_in, const int* in_sizes, int n_in,
                              void* d_out, int out_size, void* d_ws, size_t ws_size,
                              hipStream_t stream) {
    const float* X = (const float*)d_in[0];   // [16, 256, 2048]
    const float* E = (const float*)d_in[1];   // [1024, 256]
    float* out = (float*)d_out;

    char* ws = (char*)d_ws;
    int*    cnt   = (int*)   (ws + WS_CNT);
    float*  e2f   = (float*) (ws + WS_E2F);
    double* e2d   = (double*)(ws + WS_E2D);
    int*    idxws = (int*)   (ws + WS_IDX);
    int*    list  = (int*)   (ws + WS_LIST);
    uint4*  bpack = (uint4*) (ws + WS_BPACK);
    double* part  = (double*)(ws + WS_PART);

    vq_e2        <<<NK, 64, 0, stream>>>((const float4*)E, e2d, e2f, cnt);
    vq_prep_bpack<<<512, 64, 0, stream>>>((const float4*)E, bpack);
    vq_pass1     <<<NN / 128, 256, 0, stream>>>(X, bpack, e2f, idxws, cnt, list, out);
    vq_refine    <<<512, 256, 0, stream>>>(X, (const float4*)E, e2d, cnt, list, idxws, out);
    vq_gather    <<<NB * (NT / 32), 256, 0, stream>>>(X, (const float4*)E, idxws, out, part);
    vq_final     <<<1, 256, 0, stream>>>(part, out);
}